// Round 5
// baseline (785.308 us; speedup 1.0000x reference)
//
#include <hip/hip_runtime.h>
#include <hip/hip_bf16.h>

typedef unsigned short u16;
typedef __attribute__((ext_vector_type(8))) __bf16 bf16x8;
typedef __attribute__((ext_vector_type(4))) float f32x4;

typedef __attribute__((address_space(1))) const void GVoid;
typedef __attribute__((address_space(3))) void LVoid;

__device__ __forceinline__ void async_load16(const u16* g, u16* l) {
    __builtin_amdgcn_global_load_lds((GVoid*)g, (LVoid*)l, 16, 0, 0);
}

__device__ __forceinline__ float bf2f(u16 u) {
    union { unsigned i; float f; } v; v.i = ((unsigned)u) << 16; return v.f;
}
__device__ __forceinline__ u16 f2bf(float f) {
    union { float f; unsigned i; } v; v.f = f;
    unsigned r = (v.i + 0x7FFFu + ((v.i >> 16) & 1u)) >> 16;
    return (u16)r;
}
__device__ __forceinline__ float gelu_f(float x) {
    return 0.5f * x * (1.0f + erff(x * 0.70710678118654752f));
}

// element offsets inside the canonical small-vector buffer (u16, bf16 values)
#define OP_E   0
#define PT_E   2304
#define POS_E  4864
#define CTX_B  6400
#define CTX_G  7424
#define CTX_BE 8448
#define S_B1   9472
#define S_G    9984
#define S_BE   10496
#define S_B2   11008
#define D_G    11012
#define D_BE   14084
#define D_B2   17156
#define A_B1   17216
#define A_B2   17728

// ---------------------------------------------------------------------------
struct SmallTab {
    const float* src[15];
    int off[15];
    int cnt[15];
};

__global__ __launch_bounds__(256) void convert_small(SmallTab tab, u16* __restrict__ dst)
{
    int idx = blockIdx.x * 256 + threadIdx.x;
#pragma unroll
    for (int e = 0; e < 15; ++e) {
        if (idx < tab.cnt[e]) {
            dst[tab.off[e] + idx] = f2bf(tab.src[e][idx]);
            return;
        }
        idx -= tab.cnt[e];
    }
}

// ---------------------------------------------------------------------------
// Transpose fp32 weights to B^T ([N,K] row-major) bf16.
// z==8: ctx_w rows 0..1023 -> ctxWt ; z==0: sign_w1 ; z==1: aux_w1 ;
// z>=2: dig_w1[p=z-2][:1024] -> BtAll rows z*512..
// ---------------------------------------------------------------------------
__global__ __launch_bounds__(256) void transpose_all(
    const float* __restrict__ ctx_w, const float* __restrict__ sign_w1,
    const float* __restrict__ aux_w1, const float* __restrict__ dig_w1,
    u16* __restrict__ ctxWt, u16* __restrict__ BtAll)
{
    __shared__ u16 tl[32][33];
    int z = blockIdx.z;
    const float* src; u16* dst; size_t srcOff = 0; int srcLd, cols;
    if (z == 8) { src = ctx_w; dst = ctxWt; srcLd = 1024; cols = 1024; }
    else {
        srcLd = 512; cols = 512;
        if (z == 0) src = sign_w1;
        else if (z == 1) src = aux_w1;
        else { src = dig_w1; srcOff = (size_t)(z - 2) * 1280 * 512; }
        dst = BtAll + (size_t)z * 512 * 1024;
    }
    int n0 = blockIdx.x * 32;
    if (n0 >= cols) return;
    int k0 = blockIdx.y * 32;
    int t = threadIdx.x;
    int r = t >> 3;
    int c4 = (t & 7) * 4;
    float4 v = *(const float4*)&src[srcOff + (size_t)(k0 + r) * srcLd + n0 + c4];
    tl[r][c4 + 0] = f2bf(v.x); tl[r][c4 + 1] = f2bf(v.y);
    tl[r][c4 + 2] = f2bf(v.z); tl[r][c4 + 3] = f2bf(v.w);
    __syncthreads();
    ushort4 o;
    o.x = tl[c4 + 0][r]; o.y = tl[c4 + 1][r]; o.z = tl[c4 + 2][r]; o.w = tl[c4 + 3][r];
    *(ushort4*)&dst[(size_t)(n0 + r) * 1024 + k0 + c4] = o;
}

// ---------------------------------------------------------------------------
// Row-bias precompute (fp32 out)
// ---------------------------------------------------------------------------
__global__ __launch_bounds__(256) void precompute_bias(
    const float* __restrict__ ctx_w, const float* __restrict__ dig_w1,
    const float* __restrict__ op_embed, const float* __restrict__ pt_embed,
    const float* __restrict__ pos_embed, const float* __restrict__ dig_b1,
    const int* __restrict__ op_type,
    float* __restrict__ E_op, float* __restrict__ P_pt, float* __restrict__ dbias)
{
    int idx = blockIdx.x * 256 + threadIdx.x;
    if (idx < 8192) {
        int b = idx >> 10, n = idx & 1023;
        const float* e = op_embed + op_type[b] * 256;
        float s = 0.f;
        for (int q = 0; q < 256; ++q)
            s += e[q] * ctx_w[(size_t)(1024 + q) * 1024 + n];
        E_op[idx] = s;
    } else if (idx < 18432) {
        int i = idx - 8192;
        int v = i >> 10, n = i & 1023;
        const float* e = pt_embed + v * 256;
        float s = 0.f;
        for (int q = 0; q < 256; ++q)
            s += e[q] * ctx_w[(size_t)(1280 + q) * 1024 + n];
        P_pt[i] = s;
    } else if (idx < 21504) {
        int i = idx - 18432;
        int p = i >> 9, h = i & 511;
        const float* e = pos_embed + p * 256;
        float s = dig_b1[p * 512 + h];
        for (int q = 0; q < 256; ++q)
            s += e[q] * dig_w1[(size_t)p * 1280 * 512 + (size_t)(1024 + q) * 512 + h];
        dbias[i] = s;
    }
}

// ---------------------------------------------------------------------------
// Build block-diagonal W2pad [128, 4096] bf16. Row = r*16+o (role r, out o).
// r=0 sign (3 outs, K-slice [0,512)); r=1..6 digit p=r-1 ([1024+p*512,..));
// r=7 aux (1 out, [512,1024)). Zero elsewhere.
// ---------------------------------------------------------------------------
__global__ __launch_bounds__(256) void build_w2pad(
    const float* __restrict__ sign_w2, const float* __restrict__ dig_w2,
    const float* __restrict__ aux_w2, u16* __restrict__ W2pad)
{
    int idx = blockIdx.x * 256 + threadIdx.x;   // 128*4096
    int row = idx >> 12, k = idx & 4095;
    int r = row >> 4, o = row & 15;
    float v = 0.f;
    if (r == 0) {
        if (o < 3 && k < 512) v = sign_w2[k * 3 + o];
    } else if (r == 7) {
        if (o == 0 && k >= 512 && k < 1024) v = aux_w2[k - 512];
    } else {
        int p = r - 1, lo = 1024 + p * 512;
        if (o < 10 && k >= lo && k < lo + 512) v = dig_w2[(size_t)p * 5120 + (k - lo) * 10 + o];
    }
    W2pad[idx] = f2bf(v);
}

// ---------------------------------------------------------------------------
// GEMM (m97 structure): C[M,N] = A[M,K] @ Bt[N,K]^T, bf16 in, fp32 acc.
// out32: 0 -> bf16 C, 1 -> fp32 C.
// ---------------------------------------------------------------------------
__global__ __launch_bounds__(256) void gemm_bf16(
    const u16* __restrict__ A, const u16* __restrict__ Bt, void* __restrict__ C,
    int M, int N, int K, int out32)
{
    __shared__ u16 As[128 * 32];
    __shared__ u16 Bs[128 * 32];
    const int tid = threadIdx.x;
    const int wid = tid >> 6, lane = tid & 63;
    const int m0 = blockIdx.x * 128, n0 = blockIdx.y * 128;
    const int mw = (wid >> 1) * 64, nw = (wid & 1) * 64;
    const int quad = lane >> 4, r16 = lane & 15;

    f32x4 acc[4][4] = {};

    const int srow = wid * 32 + (lane >> 2);
    const int scol = (lane & 3) * 8;
    const u16* gA = A + (size_t)(m0 + srow) * K + scol;
    const u16* gB = Bt + (size_t)(n0 + srow) * K + scol;
    u16* lA = As + wid * 32 * 32;
    u16* lB = Bs + wid * 32 * 32;

    for (int k0 = 0; k0 < K; k0 += 32) {
        async_load16(gA + k0, lA);
        async_load16(gA + k0 + (size_t)16 * K, lA + 16 * 32);
        async_load16(gB + k0, lB);
        async_load16(gB + k0 + (size_t)16 * K, lB + 16 * 32);
        __syncthreads();
        bf16x8 af[4], bw[4];
#pragma unroll
        for (int i = 0; i < 4; ++i)
            af[i] = *(const bf16x8*)&As[(mw + i * 16 + r16) * 32 + quad * 8];
#pragma unroll
        for (int j = 0; j < 4; ++j)
            bw[j] = *(const bf16x8*)&Bs[(nw + j * 16 + r16) * 32 + quad * 8];
#pragma unroll
        for (int i = 0; i < 4; ++i)
#pragma unroll
            for (int j = 0; j < 4; ++j)
                acc[i][j] = __builtin_amdgcn_mfma_f32_16x16x32_bf16(
                    af[i], bw[j], acc[i][j], 0, 0, 0);
        __syncthreads();
    }

    // C/D layout: col = lane&15, row = (lane>>4)*4 + reg
#pragma unroll
    for (int i = 0; i < 4; ++i) {
#pragma unroll
        for (int j = 0; j < 4; ++j) {
            int col = n0 + nw + j * 16 + r16;
            size_t base = (size_t)(m0 + mw + i * 16 + quad * 4) * N + col;
            if (out32) {
#pragma unroll
                for (int r = 0; r < 4; ++r)
                    ((float*)C)[base + (size_t)r * N] = acc[i][j][r];
            } else {
#pragma unroll
                for (int r = 0; r < 4; ++r)
                    ((u16*)C)[base + (size_t)r * N] = f2bf(acc[i][j][r]);
            }
        }
    }
}

// ---------------------------------------------------------------------------
// ctx GEMM: A fp32 (converted in-register), B bf16 async-staged.
// ---------------------------------------------------------------------------
__global__ __launch_bounds__(256) void gemm_f32a(
    const float* __restrict__ A, const u16* __restrict__ Bt, u16* __restrict__ C,
    int M, int N, int K)
{
    __shared__ u16 As[128 * 32];
    __shared__ u16 Bs[128 * 32];
    const int tid = threadIdx.x;
    const int wid = tid >> 6, lane = tid & 63;
    const int m0 = blockIdx.x * 128, n0 = blockIdx.y * 128;
    const int mw = (wid >> 1) * 64, nw = (wid & 1) * 64;
    const int quad = lane >> 4, r16 = lane & 15;

    f32x4 acc[4][4] = {};

    const int srow = wid * 32 + (lane >> 2);
    const int scol = (lane & 3) * 8;
    const u16* gB = Bt + (size_t)(n0 + srow) * K + scol;
    u16* lB = Bs + wid * 32 * 32;

    const int r0 = tid >> 2;
    const int c8 = (tid & 3) * 8;

    for (int k0 = 0; k0 < K; k0 += 32) {
        async_load16(gB + k0, lB);
        async_load16(gB + k0 + (size_t)16 * K, lB + 16 * 32);
        const float* p0 = &A[(size_t)(m0 + r0) * K + k0 + c8];
        const float* p1 = &A[(size_t)(m0 + 64 + r0) * K + k0 + c8];
        float4 x = *(const float4*)p0, y = *(const float4*)(p0 + 4);
        float4 u = *(const float4*)p1, w = *(const float4*)(p1 + 4);
        uint4 a0, a1;
        a0.x = f2bf(x.x) | ((unsigned)f2bf(x.y) << 16);
        a0.y = f2bf(x.z) | ((unsigned)f2bf(x.w) << 16);
        a0.z = f2bf(y.x) | ((unsigned)f2bf(y.y) << 16);
        a0.w = f2bf(y.z) | ((unsigned)f2bf(y.w) << 16);
        a1.x = f2bf(u.x) | ((unsigned)f2bf(u.y) << 16);
        a1.y = f2bf(u.z) | ((unsigned)f2bf(u.w) << 16);
        a1.z = f2bf(w.x) | ((unsigned)f2bf(w.y) << 16);
        a1.w = f2bf(w.z) | ((unsigned)f2bf(w.w) << 16);
        *(uint4*)&As[r0 * 32 + c8] = a0;
        *(uint4*)&As[(64 + r0) * 32 + c8] = a1;
        __syncthreads();

        bf16x8 af[4], bw[4];
#pragma unroll
        for (int i = 0; i < 4; ++i)
            af[i] = *(const bf16x8*)&As[(mw + i * 16 + r16) * 32 + quad * 8];
#pragma unroll
        for (int j = 0; j < 4; ++j)
            bw[j] = *(const bf16x8*)&Bs[(nw + j * 16 + r16) * 32 + quad * 8];
#pragma unroll
        for (int i = 0; i < 4; ++i)
#pragma unroll
            for (int j = 0; j < 4; ++j)
                acc[i][j] = __builtin_amdgcn_mfma_f32_16x16x32_bf16(
                    af[i], bw[j], acc[i][j], 0, 0, 0);
        __syncthreads();
    }

#pragma unroll
    for (int i = 0; i < 4; ++i) {
#pragma unroll
        for (int j = 0; j < 4; ++j) {
            int col = n0 + nw + j * 16 + r16;
            size_t base = (size_t)(m0 + mw + i * 16 + quad * 4) * N + col;
#pragma unroll
            for (int r = 0; r < 4; ++r)
                C[base + (size_t)r * N] = f2bf(acc[i][j][r]);
        }
    }
}

// ---------------------------------------------------------------------------
// ctx LN+GELU
// ---------------------------------------------------------------------------
__global__ __launch_bounds__(256) void ln_ctx_kernel(
    const u16* __restrict__ pre, const float* __restrict__ E_op,
    const float* __restrict__ P_pt, const int* __restrict__ ptype,
    const u16* __restrict__ csm, u16* __restrict__ ctx, int tokOff)
{
    __shared__ float red[8];
    int local = blockIdx.x;
    int token = tokOff + local;
    int b = token >> 11;            // T = 2048
    int pt = ptype[token];
    int tid = threadIdx.x;
    int c = tid * 4;
    int wid = tid >> 6, lane = tid & 63;

    ushort4 xp = *(const ushort4*)&pre[(size_t)local * 1024 + c];
    float4 eo = *(const float4*)&E_op[b * 1024 + c];
    float4 pp = *(const float4*)&P_pt[pt * 1024 + c];
    ushort4 cb4 = *(const ushort4*)&csm[CTX_B + c];
    float x[4];
    x[0] = bf2f(xp.x) + eo.x + pp.x + bf2f(cb4.x);
    x[1] = bf2f(xp.y) + eo.y + pp.y + bf2f(cb4.y);
    x[2] = bf2f(xp.z) + eo.z + pp.z + bf2f(cb4.z);
    x[3] = bf2f(xp.w) + eo.w + pp.w + bf2f(cb4.w);

    float s = x[0] + x[1] + x[2] + x[3];
    float s2 = x[0]*x[0] + x[1]*x[1] + x[2]*x[2] + x[3]*x[3];
    for (int off = 32; off; off >>= 1) { s += __shfl_xor(s, off); s2 += __shfl_xor(s2, off); }
    if (lane == 0) { red[wid] = s; red[4 + wid] = s2; }
    __syncthreads();
    s  = red[0] + red[1] + red[2] + red[3];
    s2 = red[4] + red[5] + red[6] + red[7];
    float mean = s * (1.f / 1024.f);
    float var = fmaxf(s2 * (1.f / 1024.f) - mean * mean, 0.f);
    float rs = rsqrtf(var + 1e-5f);

    ushort4 g4 = *(const ushort4*)&csm[CTX_G + c];
    ushort4 b4 = *(const ushort4*)&csm[CTX_BE + c];
    ushort4 o;
    o.x = f2bf(gelu_f((x[0] - mean) * rs * bf2f(g4.x) + bf2f(b4.x)));
    o.y = f2bf(gelu_f((x[1] - mean) * rs * bf2f(g4.y) + bf2f(b4.y)));
    o.z = f2bf(gelu_f((x[2] - mean) * rs * bf2f(g4.z) + bf2f(b4.z)));
    o.w = f2bf(gelu_f((x[3] - mean) * rs * bf2f(g4.w) + bf2f(b4.w)));
    *(ushort4*)&ctx[(size_t)token * 1024 + c] = o;
}

// ---------------------------------------------------------------------------
// ln2: in-place bias+LN+GELU on head_pre's eight 512-slices.
// Block per token; thread t: slice s = t>>5, 16 elems at (t&31)*16.
// s=0 sign (b1+LN+gelu), s=1 aux (b1+gelu only), s=2..7 digit p=s-2
// (dbias fp32 + LN + gelu). No LDS; 32-lane shuffle reductions.
// ---------------------------------------------------------------------------
__global__ __launch_bounds__(256) void ln2_kernel(
    u16* __restrict__ hp, const u16* __restrict__ csm,
    const float* __restrict__ dbias)
{
    int token = blockIdx.x;
    int t = threadIdx.x;
    int s = t >> 5;
    int i = (t & 31) * 16;          // element base within the 512-slice
    u16* row = hp + (size_t)token * 4096 + s * 512 + i;

    uint4 l0 = ((const uint4*)row)[0];
    uint4 l1 = ((const uint4*)row)[1];
    u16 xr[16];
    *(uint4*)&xr[0] = l0; *(uint4*)&xr[8] = l1;

    float x[16];
    if (s == 0) {
#pragma unroll
        for (int j = 0; j < 16; ++j) x[j] = bf2f(xr[j]) + bf2f(csm[S_B1 + i + j]);
    } else if (s == 1) {
#pragma unroll
        for (int j = 0; j < 16; ++j) x[j] = bf2f(xr[j]) + bf2f(csm[A_B1 + i + j]);
    } else {
        int p = s - 2;
        const float* db = dbias + p * 512 + i;
#pragma unroll
        for (int j = 0; j < 16; ++j) x[j] = bf2f(xr[j]) + db[j];
    }

    u16 o[16];
    if (s == 1) {
#pragma unroll
        for (int j = 0; j < 16; ++j) o[j] = f2bf(gelu_f(x[j]));
    } else {
        float sm = 0.f, s2 = 0.f;
#pragma unroll
        for (int j = 0; j < 16; ++j) { sm += x[j]; s2 += x[j] * x[j]; }
        for (int off = 16; off; off >>= 1) { sm += __shfl_xor(sm, off); s2 += __shfl_xor(s2, off); }
        float mean = sm * (1.f / 512.f);
        float var = fmaxf(s2 * (1.f / 512.f) - mean * mean, 0.f);
        float rs = rsqrtf(var + 1e-5f);
        int gOff = (s == 0) ? (S_G + i) : (D_G + (s - 2) * 512 + i);
        int bOff = (s == 0) ? (S_BE + i) : (D_BE + (s - 2) * 512 + i);
#pragma unroll
        for (int j = 0; j < 16; ++j)
            o[j] = f2bf(gelu_f((x[j] - mean) * rs * bf2f(csm[gOff + j]) + bf2f(csm[bOff + j])));
    }
    ((uint4*)row)[0] = *(const uint4*)&o[0];
    ((uint4*)row)[1] = *(const uint4*)&o[8];
}

// ---------------------------------------------------------------------------
// gather: out_pre[Rh,128] fp32 (+bias from csm) -> final outputs.
// idx over Rh*64: c 0..2 sign, 3..62 digit, 63 aux.
// ---------------------------------------------------------------------------
__global__ __launch_bounds__(256) void gather_out(
    const float* __restrict__ out_pre, const u16* __restrict__ csm,
    float* __restrict__ out, int tokOff, int Rh)
{
    int idx = blockIdx.x * 256 + threadIdx.x;
    if (idx >= Rh * 64) return;
    int local = idx >> 6;
    int c = idx & 63;
    int token = tokOff + local;
    const float* pr = out_pre + (size_t)local * 128;
    if (c < 3) {
        out[(size_t)token * 3 + c] = pr[c] + bf2f(csm[S_B2 + c]);
    } else if (c == 63) {
        out[1032192 + (size_t)token] = pr[7 * 16] + bf2f(csm[A_B2]);
    } else {
        int d = c - 3;
        int p = d / 10, o = d - p * 10;
        out[49152 + ((size_t)token * 6 + p) * 10 + o] =
            pr[(p + 1) * 16 + o] + bf2f(csm[D_B2 + p * 10 + o]);
    }
}

// ---------------------------------------------------------------------------
extern "C" void kernel_launch(void* const* d_in, const int* in_sizes, int n_in,
                              void* d_out, int out_size, void* d_ws, size_t ws_size,
                              hipStream_t stream) {
    const float* hidden    = (const float*)d_in[0];
    const int*   op_type   = (const int*)d_in[1];
    const int*   pt_type   = (const int*)d_in[2];
    const float* op_embed  = (const float*)d_in[3];
    const float* pt_embed  = (const float*)d_in[4];
    const float* pos_embed = (const float*)d_in[5];
    const float* ctx_w     = (const float*)d_in[6];
    const float* sign_w1   = (const float*)d_in[10];
    const float* sign_w2   = (const float*)d_in[14];
    const float* dig_w1    = (const float*)d_in[16];
    const float* dig_b1    = (const float*)d_in[17];
    const float* dig_w2    = (const float*)d_in[20];
    const float* aux_w1    = (const float*)d_in[22];
    const float* aux_w2    = (const float*)d_in[24];

    char* ws = (char*)d_ws;
    u16*   ctxWt   = (u16*)(ws + 0);           //  2,097,152 (reused as W2pad later)
    u16*   BtAll   = (u16*)(ws + 2097152);     //  8,388,608  [4096,1024]
    float* E_op    = (float*)(ws + 10485760);  //     32,768
    float* P_pt    = (float*)(ws + 10518528);  //     40,960
    float* dbias   = (float*)(ws + 10559488);  //     12,288
    u16*   csm     = (u16*)(ws + 10571776);    //     65,536
    u16*   context = (u16*)(ws + 10637312);    // 33,554,432  [16384,1024]
    u16*   scratch = (u16*)(ws + 44191744);    // remainder (head_pre / ctx_pre)
    u16*   W2pad   = ctxWt;                    // overlay: ctxWt dead after ctx GEMMs
    size_t S = (ws_size > 44191744) ? ws_size - 44191744 : 0;

    int Rc = 16384;
    while ((size_t)Rc * 2048 > S && Rc > 128) Rc >>= 1;
    int Rh = 16384;
    while ((size_t)Rh * 8192 > S && Rh > 128) Rh >>= 1;

    float* out = (float*)d_out;

    SmallTab tab;
    const float* srcs[15] = { op_embed, pt_embed, pos_embed,
                              (const float*)d_in[7], (const float*)d_in[8], (const float*)d_in[9],
                              (const float*)d_in[11], (const float*)d_in[12], (const float*)d_in[13],
                              (const float*)d_in[15],
                              (const float*)d_in[18], (const float*)d_in[19], (const float*)d_in[21],
                              (const float*)d_in[23], (const float*)d_in[25] };
    const int offs[15] = { OP_E, PT_E, POS_E, CTX_B, CTX_G, CTX_BE,
                           S_B1, S_G, S_BE, S_B2,
                           D_G, D_BE, D_B2, A_B1, A_B2 };
    const int cnts[15] = { 2304, 2560, 1536, 1024, 1024, 1024,
                           512, 512, 512, 3,
                           3072, 3072, 60, 512, 1 };
    for (int i = 0; i < 15; ++i) { tab.src[i] = srcs[i]; tab.off[i] = offs[i]; tab.cnt[i] = cnts[i]; }
    convert_small<<<70, 256, 0, stream>>>(tab, csm);

    transpose_all<<<dim3(32, 32, 9), 256, 0, stream>>>(
        ctx_w, sign_w1, aux_w1, dig_w1, ctxWt, BtAll);
    precompute_bias<<<84, 256, 0, stream>>>(
        ctx_w, dig_w1, op_embed, pt_embed, pos_embed, dig_b1, op_type,
        E_op, P_pt, dbias);

    // context = gelu(LN(hidden @ ctx_w[:1024] + E_op + P_pt + b))
    for (int t0 = 0; t0 < 16384; t0 += Rc) {
        gemm_f32a<<<dim3(Rc / 128, 8), 256, 0, stream>>>(
            hidden + (size_t)t0 * 1024, ctxWt, scratch, Rc, 1024, 1024);
        ln_ctx_kernel<<<Rc, 256, 0, stream>>>(
            scratch, E_op, P_pt, pt_type, csm, context, t0);
    }

    // W2pad overlays ctxWt (now dead)
    build_w2pad<<<2048, 256, 0, stream>>>(sign_w2, dig_w2, aux_w2, W2pad);

    // head pipeline per chunk: GEMM -> ln2 -> phase-B GEMM -> gather
    for (int t0 = 0; t0 < 16384; t0 += Rh) {
        gemm_bf16<<<dim3(Rh / 128, 32), 256, 0, stream>>>(
            context + (size_t)t0 * 1024, BtAll, scratch, Rh, 4096, 1024, 0);
        ln2_kernel<<<Rh, 256, 0, stream>>>(scratch, csm, dbias);
        // out_pre overlays this chunk's (now dead) context rows
        float* out_pre = (float*)(context + (size_t)t0 * 1024);
        gemm_bf16<<<dim3(Rh / 128, 1), 256, 0, stream>>>(
            scratch, W2pad, out_pre, Rh, 128, 4096, 1);
        gather_out<<<(Rh * 64 + 255) / 256, 256, 0, stream>>>(
            out_pre, csm, out, t0, Rh);
    }
}

// Round 8
// 564.499 us; speedup vs baseline: 1.3912x; 1.3912x over previous
//
#include <hip/hip_runtime.h>
#include <hip/hip_bf16.h>

typedef unsigned short u16;
typedef __attribute__((ext_vector_type(8))) __bf16 bf16x8;
typedef __attribute__((ext_vector_type(4))) float f32x4;

typedef __attribute__((address_space(1))) const void GVoid;
typedef __attribute__((address_space(3))) void LVoid;

__device__ __forceinline__ void async_load16(const u16* g, u16* l) {
    __builtin_amdgcn_global_load_lds((GVoid*)g, (LVoid*)l, 16, 0, 0);
}

__device__ __forceinline__ float bf2f(u16 u) {
    union { unsigned i; float f; } v; v.i = ((unsigned)u) << 16; return v.f;
}
__device__ __forceinline__ u16 f2bf(float f) {
    union { float f; unsigned i; } v; v.f = f;
    unsigned r = (v.i + 0x7FFFu + ((v.i >> 16) & 1u)) >> 16;
    return (u16)r;
}
// tanh-form GELU: gelu = x*(1 - 1/(1+e^{2t})), t=0.79788x+0.035677x^3
// max |err| vs exact erf-GELU ~1e-3, far below bf16 rounding here.
__device__ __forceinline__ float gelu_f(float x) {
    float t = x * fmaf(0.0356774081f, x * x, 0.7978845608f);
    float e = __expf(2.0f * t);
    float r = 1.0f / (e + 1.0f);
    return x - x * r;
}

// element offsets inside the canonical small-vector buffer (u16, bf16 values)
#define OP_E   0
#define PT_E   2304
#define POS_E  4864
#define CTX_B  6400
#define CTX_G  7424
#define CTX_BE 8448
#define S_B1   9472
#define S_G    9984
#define S_BE   10496
#define S_B2   11008
#define D_G    11012
#define D_BE   14084
#define D_B2   17156
#define A_B1   17216
#define A_B2   17728

// ---------------------------------------------------------------------------
struct SmallTab {
    const float* src[15];
    int off[15];
    int cnt[15];
};

__global__ __launch_bounds__(256) void convert_small(SmallTab tab, u16* __restrict__ dst)
{
    int idx = blockIdx.x * 256 + threadIdx.x;
#pragma unroll
    for (int e = 0; e < 15; ++e) {
        if (idx < tab.cnt[e]) {
            dst[tab.off[e] + idx] = f2bf(tab.src[e][idx]);
            return;
        }
        idx -= tab.cnt[e];
    }
}

// ---------------------------------------------------------------------------
// Transpose fp32 weights to B^T ([N,K] row-major) bf16.
// ---------------------------------------------------------------------------
__global__ __launch_bounds__(256) void transpose_all(
    const float* __restrict__ ctx_w, const float* __restrict__ sign_w1,
    const float* __restrict__ aux_w1, const float* __restrict__ dig_w1,
    u16* __restrict__ ctxWt, u16* __restrict__ BtAll)
{
    __shared__ u16 tl[32][33];
    int z = blockIdx.z;
    const float* src; u16* dst; size_t srcOff = 0; int srcLd, cols;
    if (z == 8) { src = ctx_w; dst = ctxWt; srcLd = 1024; cols = 1024; }
    else {
        srcLd = 512; cols = 512;
        if (z == 0) src = sign_w1;
        else if (z == 1) src = aux_w1;
        else { src = dig_w1; srcOff = (size_t)(z - 2) * 1280 * 512; }
        dst = BtAll + (size_t)z * 512 * 1024;
    }
    int n0 = blockIdx.x * 32;
    if (n0 >= cols) return;
    int k0 = blockIdx.y * 32;
    int t = threadIdx.x;
    int r = t >> 3;
    int c4 = (t & 7) * 4;
    float4 v = *(const float4*)&src[srcOff + (size_t)(k0 + r) * srcLd + n0 + c4];
    tl[r][c4 + 0] = f2bf(v.x); tl[r][c4 + 1] = f2bf(v.y);
    tl[r][c4 + 2] = f2bf(v.z); tl[r][c4 + 3] = f2bf(v.w);
    __syncthreads();
    ushort4 o;
    o.x = tl[c4 + 0][r]; o.y = tl[c4 + 1][r]; o.z = tl[c4 + 2][r]; o.w = tl[c4 + 3][r];
    *(ushort4*)&dst[(size_t)(n0 + r) * 1024 + k0 + c4] = o;
}

// ---------------------------------------------------------------------------
// Row-bias precompute (fp32 out)
// ---------------------------------------------------------------------------
__global__ __launch_bounds__(256) void precompute_bias(
    const float* __restrict__ ctx_w, const float* __restrict__ dig_w1,
    const float* __restrict__ op_embed, const float* __restrict__ pt_embed,
    const float* __restrict__ pos_embed, const float* __restrict__ dig_b1,
    const int* __restrict__ op_type,
    float* __restrict__ E_op, float* __restrict__ P_pt, float* __restrict__ dbias)
{
    int idx = blockIdx.x * 256 + threadIdx.x;
    if (idx < 8192) {
        int b = idx >> 10, n = idx & 1023;
        const float* e = op_embed + op_type[b] * 256;
        float s = 0.f;
        for (int q = 0; q < 256; ++q)
            s += e[q] * ctx_w[(size_t)(1024 + q) * 1024 + n];
        E_op[idx] = s;
    } else if (idx < 18432) {
        int i = idx - 8192;
        int v = i >> 10, n = i & 1023;
        const float* e = pt_embed + v * 256;
        float s = 0.f;
        for (int q = 0; q < 256; ++q)
            s += e[q] * ctx_w[(size_t)(1280 + q) * 1024 + n];
        P_pt[i] = s;
    } else if (idx < 21504) {
        int i = idx - 18432;
        int p = i >> 9, h = i & 511;
        const float* e = pos_embed + p * 256;
        float s = dig_b1[p * 512 + h];
        for (int q = 0; q < 256; ++q)
            s += e[q] * dig_w1[(size_t)p * 1280 * 512 + (size_t)(1024 + q) * 512 + h];
        dbias[i] = s;
    }
}

// ---------------------------------------------------------------------------
// Unified per-column vectors over the 4096 head_pre columns (fp32).
// ---------------------------------------------------------------------------
__global__ __launch_bounds__(256) void build_vec(
    const u16* __restrict__ csm, const float* __restrict__ dbias,
    float* __restrict__ biasAll, float* __restrict__ gammaAll,
    float* __restrict__ betaAll)
{
    int n = blockIdx.x * 256 + threadIdx.x;   // 0..4095
    float bi, g, be;
    if (n < 512) {
        bi = bf2f(csm[S_B1 + n]); g = bf2f(csm[S_G + n]); be = bf2f(csm[S_BE + n]);
    } else if (n < 1024) {
        bi = bf2f(csm[A_B1 + n - 512]); g = 1.f; be = 0.f;
    } else {
        int h = n - 1024;
        bi = dbias[h]; g = bf2f(csm[D_G + h]); be = bf2f(csm[D_BE + h]);
    }
    biasAll[n] = bi; gammaAll[n] = g; betaAll[n] = be;
}

// ---------------------------------------------------------------------------
// Build block-diagonal W2pad [128, 4096] bf16. Row = r*16+o.
// ---------------------------------------------------------------------------
__global__ __launch_bounds__(256) void build_w2pad(
    const float* __restrict__ sign_w2, const float* __restrict__ dig_w2,
    const float* __restrict__ aux_w2, u16* __restrict__ W2pad)
{
    int idx = blockIdx.x * 256 + threadIdx.x;   // 128*4096
    int row = idx >> 12, k = idx & 4095;
    int r = row >> 4, o = row & 15;
    float v = 0.f;
    if (r == 0) {
        if (o < 3 && k < 512) v = sign_w2[k * 3 + o];
    } else if (r == 7) {
        if (o == 0 && k >= 512 && k < 1024) v = aux_w2[k - 512];
    } else {
        int p = r - 1, lo = 1024 + p * 512;
        if (o < 10 && k >= lo && k < lo + 512) v = dig_w2[(size_t)p * 5120 + (k - lo) * 10 + o];
    }
    W2pad[idx] = f2bf(v);
}

// ---------------------------------------------------------------------------
// Head GEMM (m97 structure): C[M,N] = A[M,K] @ Bt[N,K]^T, bf16 in/out.
// ---------------------------------------------------------------------------
__global__ __launch_bounds__(256) void gemm_bf16(
    const u16* __restrict__ A, const u16* __restrict__ Bt, u16* __restrict__ C,
    int M, int N, int K)
{
    __shared__ u16 As[128 * 32];
    __shared__ u16 Bs[128 * 32];
    const int tid = threadIdx.x;
    const int wid = tid >> 6, lane = tid & 63;
    const int m0 = blockIdx.x * 128, n0 = blockIdx.y * 128;
    const int mw = (wid >> 1) * 64, nw = (wid & 1) * 64;
    const int quad = lane >> 4, r16 = lane & 15;

    f32x4 acc[4][4] = {};

    const int srow = wid * 32 + (lane >> 2);
    const int scol = (lane & 3) * 8;
    const u16* gA = A + (size_t)(m0 + srow) * K + scol;
    const u16* gB = Bt + (size_t)(n0 + srow) * K + scol;
    u16* lA = As + wid * 32 * 32;
    u16* lB = Bs + wid * 32 * 32;

    for (int k0 = 0; k0 < K; k0 += 32) {
        async_load16(gA + k0, lA);
        async_load16(gA + k0 + (size_t)16 * K, lA + 16 * 32);
        async_load16(gB + k0, lB);
        async_load16(gB + k0 + (size_t)16 * K, lB + 16 * 32);
        __syncthreads();
        bf16x8 af[4], bw[4];
#pragma unroll
        for (int i = 0; i < 4; ++i)
            af[i] = *(const bf16x8*)&As[(mw + i * 16 + r16) * 32 + quad * 8];
#pragma unroll
        for (int j = 0; j < 4; ++j)
            bw[j] = *(const bf16x8*)&Bs[(nw + j * 16 + r16) * 32 + quad * 8];
#pragma unroll
        for (int i = 0; i < 4; ++i)
#pragma unroll
            for (int j = 0; j < 4; ++j)
                acc[i][j] = __builtin_amdgcn_mfma_f32_16x16x32_bf16(
                    af[i], bw[j], acc[i][j], 0, 0, 0);
        __syncthreads();
    }

#pragma unroll
    for (int i = 0; i < 4; ++i) {
#pragma unroll
        for (int j = 0; j < 4; ++j) {
            int col = n0 + nw + j * 16 + r16;
            size_t base = (size_t)(m0 + mw + i * 16 + quad * 4) * N + col;
#pragma unroll
            for (int r = 0; r < 4; ++r)
                C[base + (size_t)r * N] = f2bf(acc[i][j][r]);
        }
    }
}

// ---------------------------------------------------------------------------
// ctx GEMM: A fp32 (converted in-register), B bf16 async-staged.
// ---------------------------------------------------------------------------
__global__ __launch_bounds__(256) void gemm_f32a(
    const float* __restrict__ A, const u16* __restrict__ Bt, u16* __restrict__ C,
    int M, int N, int K)
{
    __shared__ u16 As[128 * 32];
    __shared__ u16 Bs[128 * 32];
    const int tid = threadIdx.x;
    const int wid = tid >> 6, lane = tid & 63;
    const int m0 = blockIdx.x * 128, n0 = blockIdx.y * 128;
    const int mw = (wid >> 1) * 64, nw = (wid & 1) * 64;
    const int quad = lane >> 4, r16 = lane & 15;

    f32x4 acc[4][4] = {};

    const int srow = wid * 32 + (lane >> 2);
    const int scol = (lane & 3) * 8;
    const u16* gB = Bt + (size_t)(n0 + srow) * K + scol;
    u16* lB = Bs + wid * 32 * 32;

    const int r0 = tid >> 2;
    const int c8 = (tid & 3) * 8;

    for (int k0 = 0; k0 < K; k0 += 32) {
        async_load16(gB + k0, lB);
        async_load16(gB + k0 + (size_t)16 * K, lB + 16 * 32);
        const float* p0 = &A[(size_t)(m0 + r0) * K + k0 + c8];
        const float* p1 = &A[(size_t)(m0 + 64 + r0) * K + k0 + c8];
        float4 x = *(const float4*)p0, y = *(const float4*)(p0 + 4);
        float4 u = *(const float4*)p1, w = *(const float4*)(p1 + 4);
        uint4 a0, a1;
        a0.x = f2bf(x.x) | ((unsigned)f2bf(x.y) << 16);
        a0.y = f2bf(x.z) | ((unsigned)f2bf(x.w) << 16);
        a0.z = f2bf(y.x) | ((unsigned)f2bf(y.y) << 16);
        a0.w = f2bf(y.z) | ((unsigned)f2bf(y.w) << 16);
        a1.x = f2bf(u.x) | ((unsigned)f2bf(u.y) << 16);
        a1.y = f2bf(u.z) | ((unsigned)f2bf(u.w) << 16);
        a1.z = f2bf(w.x) | ((unsigned)f2bf(w.y) << 16);
        a1.w = f2bf(w.z) | ((unsigned)f2bf(w.w) << 16);
        *(uint4*)&As[r0 * 32 + c8] = a0;
        *(uint4*)&As[(64 + r0) * 32 + c8] = a1;
        __syncthreads();

        bf16x8 af[4], bw[4];
#pragma unroll
        for (int i = 0; i < 4; ++i)
            af[i] = *(const bf16x8*)&As[(mw + i * 16 + r16) * 32 + quad * 8];
#pragma unroll
        for (int j = 0; j < 4; ++j)
            bw[j] = *(const bf16x8*)&Bs[(nw + j * 16 + r16) * 32 + quad * 8];
#pragma unroll
        for (int i = 0; i < 4; ++i)
#pragma unroll
            for (int j = 0; j < 4; ++j)
                acc[i][j] = __builtin_amdgcn_mfma_f32_16x16x32_bf16(
                    af[i], bw[j], acc[i][j], 0, 0, 0);
        __syncthreads();
    }

#pragma unroll
    for (int i = 0; i < 4; ++i) {
#pragma unroll
        for (int j = 0; j < 4; ++j) {
            int col = n0 + nw + j * 16 + r16;
            size_t base = (size_t)(m0 + mw + i * 16 + quad * 4) * N + col;
#pragma unroll
            for (int r = 0; r < 4; ++r)
                C[base + (size_t)r * N] = f2bf(acc[i][j][r]);
        }
    }
}

// ---------------------------------------------------------------------------
// ctx LN+GELU
// ---------------------------------------------------------------------------
__global__ __launch_bounds__(256) void ln_ctx_kernel(
    const u16* __restrict__ pre, const float* __restrict__ E_op,
    const float* __restrict__ P_pt, const int* __restrict__ ptype,
    const u16* __restrict__ csm, u16* __restrict__ ctx, int tokOff)
{
    __shared__ float red[8];
    int local = blockIdx.x;
    int token = tokOff + local;
    int b = token >> 11;            // T = 2048
    int pt = ptype[token];
    int tid = threadIdx.x;
    int c = tid * 4;
    int wid = tid >> 6, lane = tid & 63;

    ushort4 xp = *(const ushort4*)&pre[(size_t)local * 1024 + c];
    float4 eo = *(const float4*)&E_op[b * 1024 + c];
    float4 pp = *(const float4*)&P_pt[pt * 1024 + c];
    ushort4 cb4 = *(const ushort4*)&csm[CTX_B + c];
    float x[4];
    x[0] = bf2f(xp.x) + eo.x + pp.x + bf2f(cb4.x);
    x[1] = bf2f(xp.y) + eo.y + pp.y + bf2f(cb4.y);
    x[2] = bf2f(xp.z) + eo.z + pp.z + bf2f(cb4.z);
    x[3] = bf2f(xp.w) + eo.w + pp.w + bf2f(cb4.w);

    float s = x[0] + x[1] + x[2] + x[3];
    float s2 = x[0]*x[0] + x[1]*x[1] + x[2]*x[2] + x[3]*x[3];
    for (int off = 32; off; off >>= 1) { s += __shfl_xor(s, off); s2 += __shfl_xor(s2, off); }
    if (lane == 0) { red[wid] = s; red[4 + wid] = s2; }
    __syncthreads();
    s  = red[0] + red[1] + red[2] + red[3];
    s2 = red[4] + red[5] + red[6] + red[7];
    float mean = s * (1.f / 1024.f);
    float var = fmaxf(s2 * (1.f / 1024.f) - mean * mean, 0.f);
    float rs = rsqrtf(var + 1e-5f);

    ushort4 g4 = *(const ushort4*)&csm[CTX_G + c];
    ushort4 b4 = *(const ushort4*)&csm[CTX_BE + c];
    ushort4 o;
    o.x = f2bf(gelu_f((x[0] - mean) * rs * bf2f(g4.x) + bf2f(b4.x)));
    o.y = f2bf(gelu_f((x[1] - mean) * rs * bf2f(g4.y) + bf2f(b4.y)));
    o.z = f2bf(gelu_f((x[2] - mean) * rs * bf2f(g4.z) + bf2f(b4.z)));
    o.w = f2bf(gelu_f((x[3] - mean) * rs * bf2f(g4.w) + bf2f(b4.w)));
    *(ushort4*)&ctx[(size_t)token * 1024 + c] = o;
}

// ---------------------------------------------------------------------------
// ln_stats: per (token, 512-slice) mean/rstd of (x + biasAll). One wave per
// (token,slice); aux slice (s==1) gets identity stats. Pure streaming read.
// ---------------------------------------------------------------------------
__global__ __launch_bounds__(256) void ln_stats(
    const u16* __restrict__ hp, const float* __restrict__ biasAll,
    float2* __restrict__ stats, int Rh)
{
    int wid = threadIdx.x >> 6, lane = threadIdx.x & 63;
    int idx = blockIdx.x * 4 + wid;            // < Rh*8
    int token = idx >> 3, s = idx & 7;
    const u16* row = hp + (size_t)token * 4096 + s * 512 + lane * 8;
    ushort4 a = ((const ushort4*)row)[0];
    ushort4 b = ((const ushort4*)row)[1];
    u16 xr[8]; *(ushort4*)&xr[0] = a; *(ushort4*)&xr[4] = b;
    const float* bi = biasAll + s * 512 + lane * 8;
    float4 b0 = *(const float4*)bi, b1 = *(const float4*)(bi + 4);
    float bb[8] = {b0.x, b0.y, b0.z, b0.w, b1.x, b1.y, b1.z, b1.w};
    float sm = 0.f, s2 = 0.f;
#pragma unroll
    for (int j = 0; j < 8; ++j) {
        float v = bf2f(xr[j]) + bb[j];
        sm += v; s2 += v * v;
    }
    for (int off = 32; off; off >>= 1) { sm += __shfl_xor(sm, off); s2 += __shfl_xor(s2, off); }
    if (lane == 0) {
        float mean = sm * (1.f / 512.f);
        float var = fmaxf(s2 * (1.f / 512.f) - mean * mean, 0.f);
        float2 st = make_float2(mean, rsqrtf(var + 1e-5f));
        if (s == 1) st = make_float2(0.f, 1.f);   // aux slice: identity stats
        stats[idx] = st;
    }
}

// ---------------------------------------------------------------------------
// gemm_final: out_pre[ks][Rh][128] = gelu(LN(A))@W2pad^T, K-split by 4.
// A-staging applies (x+bias-mean)*rs*gamma+beta then GELU on the fly.
// ---------------------------------------------------------------------------
__global__ __launch_bounds__(256) void gemm_final(
    const u16* __restrict__ A, const u16* __restrict__ W2pad,
    const float* __restrict__ biasAll, const float* __restrict__ gammaAll,
    const float* __restrict__ betaAll, const float2* __restrict__ stats,
    float* __restrict__ out_pre, int Rh)
{
    __shared__ u16 As[128 * 32];
    __shared__ u16 Bs[128 * 32];
    const int tid = threadIdx.x;
    const int wid = tid >> 6, lane = tid & 63;
    const int m0 = blockIdx.x * 128;
    const int ks = blockIdx.y, kbase = ks * 1024;
    const int mw = (wid >> 1) * 64, nw = (wid & 1) * 64;
    const int quad = lane >> 4, r16 = lane & 15;

    f32x4 acc[4][4] = {};

    const int srow = wid * 32 + (lane >> 2);
    const int scol = (lane & 3) * 8;
    const u16* gB = W2pad + (size_t)srow * 4096 + kbase + scol;
    u16* lB = Bs + wid * 32 * 32;

    const int r0 = tid >> 2;
    const int c8 = (tid & 3) * 8;

    for (int k0 = 0; k0 < 1024; k0 += 32) {
        async_load16(gB + k0, lB);
        async_load16(gB + k0 + (size_t)16 * 4096, lB + 16 * 32);
        int kk = kbase + k0 + c8;
        int sl = kk >> 9;
        float4 bi0 = *(const float4*)&biasAll[kk], bi1 = *(const float4*)&biasAll[kk + 4];
        float4 g0 = *(const float4*)&gammaAll[kk], g1 = *(const float4*)&gammaAll[kk + 4];
        float4 be0 = *(const float4*)&betaAll[kk], be1 = *(const float4*)&betaAll[kk + 4];
        float bb[8] = {bi0.x, bi0.y, bi0.z, bi0.w, bi1.x, bi1.y, bi1.z, bi1.w};
        float gg[8] = {g0.x, g0.y, g0.z, g0.w, g1.x, g1.y, g1.z, g1.w};
        float bt[8] = {be0.x, be0.y, be0.z, be0.w, be1.x, be1.y, be1.z, be1.w};
#pragma unroll
        for (int h = 0; h < 2; ++h) {
            int row = m0 + r0 + h * 64;
            const u16* ap = A + (size_t)row * 4096 + kk;
            ushort4 xa = ((const ushort4*)ap)[0];
            ushort4 xb = ((const ushort4*)ap)[1];
            u16 xr[8]; *(ushort4*)&xr[0] = xa; *(ushort4*)&xr[4] = xb;
            float2 st = stats[row * 8 + sl];
            u16 o[8];
#pragma unroll
            for (int j = 0; j < 8; ++j) {
                float v = (bf2f(xr[j]) + bb[j] - st.x) * st.y * gg[j] + bt[j];
                o[j] = f2bf(gelu_f(v));
            }
            *(uint4*)&As[(h * 64 + r0) * 32 + c8] = *(const uint4*)&o[0];
        }
        __syncthreads();

        bf16x8 af[4], bw[4];
#pragma unroll
        for (int i = 0; i < 4; ++i)
            af[i] = *(const bf16x8*)&As[(mw + i * 16 + r16) * 32 + quad * 8];
#pragma unroll
        for (int j = 0; j < 4; ++j)
            bw[j] = *(const bf16x8*)&Bs[(nw + j * 16 + r16) * 32 + quad * 8];
#pragma unroll
        for (int i = 0; i < 4; ++i)
#pragma unroll
            for (int j = 0; j < 4; ++j)
                acc[i][j] = __builtin_amdgcn_mfma_f32_16x16x32_bf16(
                    af[i], bw[j], acc[i][j], 0, 0, 0);
        __syncthreads();
    }

    float* op = out_pre + (size_t)ks * Rh * 128;
#pragma unroll
    for (int i = 0; i < 4; ++i) {
#pragma unroll
        for (int j = 0; j < 4; ++j) {
            int col = nw + j * 16 + r16;
            size_t base = (size_t)(m0 + mw + i * 16 + quad * 4) * 128 + col;
#pragma unroll
            for (int r = 0; r < 4; ++r)
                op[base + (size_t)r * 128] = acc[i][j][r];
        }
    }
}

// ---------------------------------------------------------------------------
// gather: sum 4 K-split planes of out_pre[ks][Rh][128] + out-bias -> outputs.
// ---------------------------------------------------------------------------
__global__ __launch_bounds__(256) void gather_out(
    const float* __restrict__ out_pre, const u16* __restrict__ csm,
    float* __restrict__ out, int tokOff, int Rh)
{
    int idx = blockIdx.x * 256 + threadIdx.x;
    if (idx >= Rh * 64) return;
    int local = idx >> 6;
    int c = idx & 63;
    int token = tokOff + local;
    size_t P = (size_t)Rh * 128;
    size_t base = (size_t)local * 128;
    int col;
    if (c < 3) col = c;
    else if (c == 63) col = 7 * 16;
    else { int d = c - 3; int p = d / 10; col = (p + 1) * 16 + (d - p * 10); }
    float v = out_pre[base + col] + out_pre[P + base + col]
            + out_pre[2 * P + base + col] + out_pre[3 * P + base + col];
    if (c < 3) {
        out[(size_t)token * 3 + c] = v + bf2f(csm[S_B2 + c]);
    } else if (c == 63) {
        out[1032192 + (size_t)token] = v + bf2f(csm[A_B2]);
    } else {
        int d = c - 3;
        int p = d / 10, o = d - p * 10;
        out[49152 + ((size_t)token * 6 + p) * 10 + o] = v + bf2f(csm[D_B2 + p * 10 + o]);
    }
}

// ---------------------------------------------------------------------------
extern "C" void kernel_launch(void* const* d_in, const int* in_sizes, int n_in,
                              void* d_out, int out_size, void* d_ws, size_t ws_size,
                              hipStream_t stream) {
    const float* hidden    = (const float*)d_in[0];
    const int*   op_type   = (const int*)d_in[1];
    const int*   pt_type   = (const int*)d_in[2];
    const float* op_embed  = (const float*)d_in[3];
    const float* pt_embed  = (const float*)d_in[4];
    const float* pos_embed = (const float*)d_in[5];
    const float* ctx_w     = (const float*)d_in[6];
    const float* sign_w1   = (const float*)d_in[10];
    const float* sign_w2   = (const float*)d_in[14];
    const float* dig_w1    = (const float*)d_in[16];
    const float* dig_b1    = (const float*)d_in[17];
    const float* dig_w2    = (const float*)d_in[20];
    const float* aux_w1    = (const float*)d_in[22];
    const float* aux_w2    = (const float*)d_in[24];

    char* ws = (char*)d_ws;
    u16*    ctxWt    = (u16*)(ws + 0);           //  2,097,152 (later W2pad overlay)
    u16*    BtAll    = (u16*)(ws + 2097152);     //  8,388,608
    float*  E_op     = (float*)(ws + 10485760);  //     32,768
    float*  P_pt     = (float*)(ws + 10518528);  //     40,960
    float*  dbias    = (float*)(ws + 10559488);  //     12,288
    u16*    csm      = (u16*)(ws + 10571776);    //     65,536
    float*  biasAll  = (float*)(ws + 10637312);  //     16,384
    float*  gammaAll = (float*)(ws + 10653696);  //     16,384
    float*  betaAll  = (float*)(ws + 10670080);  //     16,384
    float2* stats    = (float2*)(ws + 10686464); //  1,048,576 (max Rh*8*8)
    u16*    context  = (u16*)(ws + 11735040);    // 33,554,432
    u16*    scratch  = (u16*)(ws + 45289472);    // remainder (head_pre / ctx_pre)
    u16*    W2pad    = ctxWt;
    size_t S = (ws_size > 45289472) ? ws_size - 45289472 : 0;

    int Rc = 16384;
    while ((size_t)Rc * 2048 > S && Rc > 128) Rc >>= 1;
    int Rh = 16384;
    while ((size_t)Rh * 8192 > S && Rh > 128) Rh >>= 1;

    float* out = (float*)d_out;

    SmallTab tab;
    const float* srcs[15] = { op_embed, pt_embed, pos_embed,
                              (const float*)d_in[7], (const float*)d_in[8], (const float*)d_in[9],
                              (const float*)d_in[11], (const float*)d_in[12], (const float*)d_in[13],
                              (const float*)d_in[15],
                              (const float*)d_in[18], (const float*)d_in[19], (const float*)d_in[21],
                              (const float*)d_in[23], (const float*)d_in[25] };
    const int offs[15] = { OP_E, PT_E, POS_E, CTX_B, CTX_G, CTX_BE,
                           S_B1, S_G, S_BE, S_B2,
                           D_G, D_BE, D_B2, A_B1, A_B2 };
    const int cnts[15] = { 2304, 2560, 1536, 1024, 1024, 1024,
                           512, 512, 512, 3,
                           3072, 3072, 60, 512, 1 };
    for (int i = 0; i < 15; ++i) { tab.src[i] = srcs[i]; tab.off[i] = offs[i]; tab.cnt[i] = cnts[i]; }
    convert_small<<<70, 256, 0, stream>>>(tab, csm);

    transpose_all<<<dim3(32, 32, 9), 256, 0, stream>>>(
        ctx_w, sign_w1, aux_w1, dig_w1, ctxWt, BtAll);
    precompute_bias<<<84, 256, 0, stream>>>(
        ctx_w, dig_w1, op_embed, pt_embed, pos_embed, dig_b1, op_type,
        E_op, P_pt, dbias);
    build_vec<<<16, 256, 0, stream>>>(csm, dbias, biasAll, gammaAll, betaAll);

    // context = gelu(LN(hidden @ ctx_w[:1024] + E_op + P_pt + b))
    for (int t0 = 0; t0 < 16384; t0 += Rc) {
        gemm_f32a<<<dim3(Rc / 128, 8), 256, 0, stream>>>(
            hidden + (size_t)t0 * 1024, ctxWt, scratch, Rc, 1024, 1024);
        ln_ctx_kernel<<<Rc, 256, 0, stream>>>(
            scratch, E_op, P_pt, pt_type, csm, context, t0);
    }

    // W2pad overlays ctxWt (now dead)
    build_w2pad<<<2048, 256, 0, stream>>>(sign_w2, dig_w2, aux_w2, W2pad);

    // head pipeline per chunk: GEMM -> stats -> fused LN+GELU GEMM -> gather
    for (int t0 = 0; t0 < 16384; t0 += Rh) {
        gemm_bf16<<<dim3(Rh / 128, 32), 256, 0, stream>>>(
            context + (size_t)t0 * 1024, BtAll, scratch, Rh, 4096, 1024);
        ln_stats<<<Rh * 2, 256, 0, stream>>>(scratch, biasAll, stats, Rh);
        // out_pre overlays this chunk's (now dead) context rows: 4*Rh*128*4 B == Rh*2048 B
        float* out_pre = (float*)(context + (size_t)t0 * 1024);
        gemm_final<<<dim3(Rh / 128, 4), 256, 0, stream>>>(
            scratch, W2pad, biasAll, gammaAll, betaAll, stats, out_pre, Rh);
        gather_out<<<(Rh * 64 + 255) / 256, 256, 0, stream>>>(
            out_pre, csm, out, t0, Rh);
    }
}